// Round 1
// baseline (439.236 us; speedup 1.0000x reference)
//
#include <hip/hip_runtime.h>
#include <cstdint>
#include <cstddef>

typedef __bf16 bf16;
typedef __attribute__((ext_vector_type(8))) __bf16 bf16x8;
typedef __attribute__((ext_vector_type(4))) float f32x4;

#define S_LEN   2048
#define WIN     512
#define NH_Q    16
#define NH_KV   4
#define HD_     128
#define NTOK    4096   // B * S

// async global->LDS, 16B per lane; LDS dest = wave-uniform base + lane*16
__device__ __forceinline__ void async_copy16(const void* g, void* l) {
  __builtin_amdgcn_global_load_lds(
      (const __attribute__((address_space(1))) void*)g,
      (__attribute__((address_space(3))) void*)l, 16, 0, 0);
}

// ---------------- fp32 -> bf16 convert ----------------
__global__ __launch_bounds__(256) void cvt_bf16(const float* __restrict__ in,
                                                bf16* __restrict__ out, int n) {
  int i = (blockIdx.x * 256 + threadIdx.x) * 4;
  if (i >= n) return;
  float4 v = *(const float4*)(in + i);
  out[i + 0] = (bf16)v.x;
  out[i + 1] = (bf16)v.y;
  out[i + 2] = (bf16)v.z;
  out[i + 3] = (bf16)v.w;
}

// ---------------- GEMM: C[M][N] = A[M][K] @ W[N][K]^T (both K-contiguous) ----
// m97 structure: 128x128 tile, BK=32, 4 waves in 2x2, 4x4 16x16x32 MFMAs/wave.
template <typename OutT>
__global__ __launch_bounds__(256)
void gemm_bt(const bf16* __restrict__ A, const bf16* __restrict__ W,
             OutT* __restrict__ C, int M, int N, int K) {
  __shared__ __align__(16) bf16 As[128 * 32];
  __shared__ __align__(16) bf16 Bs[128 * 32];
  const int tid  = threadIdx.x;
  const int wave = tid >> 6, lane = tid & 63;
  const int quad = lane >> 4, l16 = lane & 15;
  const int wm = wave >> 1, wn = wave & 1;
  const int m0 = blockIdx.y * 128, n0 = blockIdx.x * 128;
  const int lrow = lane >> 2;        // row within 16-row chunk
  const int lcol = (lane & 3) * 8;   // k element offset

  f32x4 acc[4][4];
#pragma unroll
  for (int i = 0; i < 4; ++i)
#pragma unroll
    for (int j = 0; j < 4; ++j) acc[i][j] = (f32x4){0.f, 0.f, 0.f, 0.f};

  for (int k0 = 0; k0 < K; k0 += 32) {
    __syncthreads();  // previous iter's frag reads done before restage
#pragma unroll
    for (int it = 0; it < 2; ++it) {
      const int c   = it * 4 + wave;   // chunk 0..7, 1024B each (16 rows)
      const int row = c * 16 + lrow;
      async_copy16(A + (size_t)(m0 + row) * K + k0 + lcol, &As[c * 512]);
      async_copy16(W + (size_t)(n0 + row) * K + k0 + lcol, &Bs[c * 512]);
    }
    __syncthreads();  // drains vmcnt before barrier -> LDS valid
    bf16x8 af[4], bfr[4];
#pragma unroll
    for (int mt = 0; mt < 4; ++mt)
      af[mt] = *(const bf16x8*)&As[(wm * 64 + mt * 16 + l16) * 32 + quad * 8];
#pragma unroll
    for (int nt = 0; nt < 4; ++nt)
      bfr[nt] = *(const bf16x8*)&Bs[(wn * 64 + nt * 16 + l16) * 32 + quad * 8];
#pragma unroll
    for (int mt = 0; mt < 4; ++mt)
#pragma unroll
      for (int nt = 0; nt < 4; ++nt)
        acc[mt][nt] = __builtin_amdgcn_mfma_f32_16x16x32_bf16(
            af[mt], bfr[nt], acc[mt][nt], 0, 0, 0);
  }
  // epilogue: C/D layout row = quad*4+reg, col = lane&15 (m89/m91 verified)
#pragma unroll
  for (int mt = 0; mt < 4; ++mt)
#pragma unroll
    for (int nt = 0; nt < 4; ++nt)
#pragma unroll
      for (int r = 0; r < 4; ++r) {
        const int row = m0 + wm * 64 + mt * 16 + quad * 4 + r;
        const int col = n0 + wn * 64 + nt * 16 + l16;
        C[(size_t)row * N + col] = (OutT)acc[mt][nt][r];
      }
}

// ---------------- partial RoPE (first 64 dims of each head) -----------------
__global__ __launch_bounds__(256)
void rope_kernel(bf16* __restrict__ buf, int nh_shift, int total) {
  int i = blockIdx.x * 256 + threadIdx.x;
  if (i >= total) return;
  int d   = i & 31;          // rotation pair index 0..31
  int t   = i >> 5;
  int h   = t & ((1 << nh_shift) - 1);
  int tok = t >> nh_shift;
  int pos = tok & (S_LEN - 1);
  // inv_freq = 10000^(-d/32) = exp2(-d * log2(10000)/32)
  float invf = exp2f(-(float)d * 0.41524101186091903f);
  float ang  = (float)pos * invf;
  float c = cosf(ang), s = sinf(ang);
  bf16* p = buf + (((size_t)tok << nh_shift) + h) * HD_;
  float x1 = (float)p[d], x2 = (float)p[d + 32];
  p[d]      = (bf16)(x1 * c - x2 * s);
  p[d + 32] = (bf16)(x2 * c + x1 * s);
}

// ---------------- flash attention, sliding window 512, GQA 4:1 --------------
// block = 4 waves; 64 queries/block (16/wave); key tiles of 64.
#define KS_STRIDE 136   // 128 + 8 pad: breaks 256B-stride bank conflicts
#define VT_STRIDE 72    // 64 + 8 pad
#define PB_STRIDE 72

__global__ __launch_bounds__(256)
void attn_kernel(const bf16* __restrict__ Qg, const bf16* __restrict__ Kg,
                 const bf16* __restrict__ Vg, bf16* __restrict__ Og) {
  __shared__ __align__(16) bf16 Ks[64 * KS_STRIDE];    // K tile [key][d]
  __shared__ __align__(16) bf16 Vt[128 * VT_STRIDE];   // V tile transposed [d][key]
  __shared__ __align__(16) bf16 Pb[4][16 * PB_STRIDE]; // per-wave P buffer

  const int tid  = threadIdx.x;
  const int wave = tid >> 6, lane = tid & 63;
  const int quad = lane >> 4, l16 = lane & 15;

  const int qt = blockIdx.x, h = blockIdx.y, b = blockIdx.z;
  const int kv = h >> 2;
  const int q0 = qt * 64;
  const int tok0 = b * S_LEN;
  const float scale = 0.08838834764831845f;  // 1/sqrt(128)

  // Q A-fragments: wave's queries q0+wave*16+l16; A[m=l16][k=quad*8+j]
  bf16x8 qf[4];
  {
    const bf16* qp = Qg + (size_t)(tok0 + q0 + wave * 16 + l16) * (NH_Q * HD_)
                     + h * HD_ + quad * 8;
#pragma unroll
    for (int kb = 0; kb < 4; ++kb) qf[kb] = *(const bf16x8*)(qp + kb * 32);
  }

  f32x4 o[8];
#pragma unroll
  for (int dt = 0; dt < 8; ++dt) o[dt] = (f32x4){0.f, 0.f, 0.f, 0.f};
  float m_run[4], l_run[4];
#pragma unroll
  for (int r = 0; r < 4; ++r) { m_run[r] = -__builtin_inff(); l_run[r] = 0.f; }

  int kt_begin = q0 - WIN;           // aligned: q0, WIN multiples of 64
  if (kt_begin < 0) kt_begin = 0;
  const int kt_end = q0 + 64;

  for (int kt = kt_begin; kt < kt_end; kt += 64) {
    __syncthreads();  // all waves done reading previous K/V tiles
    // stage K (row-major, padded) and V (transposed, padded)
#pragma unroll
    for (int it = 0; it < 4; ++it) {
      int vid  = tid + it * 256;     // 0..1023
      int key  = vid >> 4;           // 0..63
      int dblk = vid & 15;           // 8-dim block
      const size_t grow = (size_t)(tok0 + kt + key) * (NH_KV * HD_) + kv * HD_ + dblk * 8;
      bf16x8 kvec = *(const bf16x8*)(Kg + grow);
      *(bf16x8*)&Ks[key * KS_STRIDE + dblk * 8] = kvec;
      bf16x8 vvec = *(const bf16x8*)(Vg + grow);
#pragma unroll
      for (int j = 0; j < 8; ++j) Vt[(dblk * 8 + j) * VT_STRIDE + key] = vvec[j];
    }
    __syncthreads();

    // QK^T: S[q][key], 4 n-tiles of 16 keys
    f32x4 sfrag[4];
#pragma unroll
    for (int nt = 0; nt < 4; ++nt) {
      f32x4 acc = (f32x4){0.f, 0.f, 0.f, 0.f};
#pragma unroll
      for (int kb = 0; kb < 4; ++kb) {
        bf16x8 kfrag =
            *(const bf16x8*)&Ks[(nt * 16 + l16) * KS_STRIDE + kb * 32 + quad * 8];
        acc = __builtin_amdgcn_mfma_f32_16x16x32_bf16(qf[kb], kfrag, acc, 0, 0, 0);
      }
      sfrag[nt] = acc;
    }
    // scale + causal/window mask (query = qbase+r, key = kt+nt*16+l16)
    const int qbase = q0 + wave * 16 + quad * 4;
#pragma unroll
    for (int nt = 0; nt < 4; ++nt) {
      int key = kt + nt * 16 + l16;
#pragma unroll
      for (int r = 0; r < 4; ++r) {
        int q = qbase + r;
        bool ok = (key <= q) && (key > q - WIN);
        sfrag[nt][r] = ok ? sfrag[nt][r] * scale : -__builtin_inff();
      }
    }
    // online softmax (rows live in 16-lane groups; reduce via shfl_xor 1..8)
    float pv[4][4], alpha[4];
#pragma unroll
    for (int r = 0; r < 4; ++r) {
      float mx = fmaxf(fmaxf(sfrag[0][r], sfrag[1][r]),
                       fmaxf(sfrag[2][r], sfrag[3][r]));
      for (int off = 1; off < 16; off <<= 1) mx = fmaxf(mx, __shfl_xor(mx, off, 64));
      float mnew = fmaxf(m_run[r], mx);
      float msub = (mnew == -__builtin_inff()) ? 0.f : mnew;  // NaN guard
      alpha[r] = __expf(m_run[r] - msub);   // exp(-inf)=0 on first tile
      m_run[r] = mnew;
      float psum = 0.f;
#pragma unroll
      for (int nt = 0; nt < 4; ++nt) {
        float p = __expf(sfrag[nt][r] - msub);  // masked: exp(-inf)=0
        pv[nt][r] = p;
        psum += p;
      }
      for (int off = 1; off < 16; off <<= 1) psum += __shfl_xor(psum, off, 64);
      l_run[r] = l_run[r] * alpha[r] + psum;
    }
    // rescale O
#pragma unroll
    for (int dt = 0; dt < 8; ++dt)
#pragma unroll
      for (int r = 0; r < 4; ++r) o[dt][r] *= alpha[r];
    // P: C-layout -> LDS -> A-layout (m120-verified transform)
#pragma unroll
    for (int nt = 0; nt < 4; ++nt)
#pragma unroll
      for (int r = 0; r < 4; ++r)
        Pb[wave][(quad * 4 + r) * PB_STRIDE + nt * 16 + l16] = (bf16)pv[nt][r];
    __syncthreads();  // in-wave hazard; uniform, cheap, safe
    bf16x8 pf[2];
    pf[0] = *(const bf16x8*)&Pb[wave][l16 * PB_STRIDE + quad * 8];
    pf[1] = *(const bf16x8*)&Pb[wave][l16 * PB_STRIDE + 32 + quad * 8];
    // PV: O[q][d] += P[q][key] * V[key][d]; B-frag from Vt rows (contiguous)
#pragma unroll
    for (int dt = 0; dt < 8; ++dt)
#pragma unroll
      for (int kb = 0; kb < 2; ++kb) {
        bf16x8 vfrag =
            *(const bf16x8*)&Vt[(dt * 16 + l16) * VT_STRIDE + kb * 32 + quad * 8];
        o[dt] = __builtin_amdgcn_mfma_f32_16x16x32_bf16(pf[kb], vfrag, o[dt], 0, 0, 0);
      }
  }
  // epilogue: divide by l, write bf16
  const int qrow = tok0 + q0 + wave * 16 + quad * 4;
#pragma unroll
  for (int r = 0; r < 4; ++r) {
    float inv = 1.f / l_run[r];
#pragma unroll
    for (int dt = 0; dt < 8; ++dt)
      Og[(size_t)(qrow + r) * (NH_Q * HD_) + h * HD_ + dt * 16 + l16] =
          (bf16)(o[dt][r] * inv);
  }
}

// ---------------- launcher ----------------
extern "C" void kernel_launch(void* const* d_in, const int* in_sizes, int n_in,
                              void* d_out, int out_size, void* d_ws, size_t ws_size,
                              hipStream_t stream) {
  const float* hs = (const float*)d_in[0];
  const float* Wq = (const float*)d_in[1];
  const float* Wk = (const float*)d_in[2];
  const float* Wv = (const float*)d_in[3];
  const float* Wo = (const float*)d_in[4];
  float* out = (float*)d_out;

  char* w = (char*)d_ws;
  bf16* hsb = (bf16*)w; w += (size_t)NTOK * 2048 * 2;
  bf16* wqb = (bf16*)w; w += (size_t)2048 * 2048 * 2;
  bf16* wkb = (bf16*)w; w += (size_t)512 * 2048 * 2;
  bf16* wvb = (bf16*)w; w += (size_t)512 * 2048 * 2;
  bf16* wob = (bf16*)w; w += (size_t)2048 * 2048 * 2;
  bf16* qb  = (bf16*)w; w += (size_t)NTOK * 2048 * 2;
  bf16* kb  = (bf16*)w; w += (size_t)NTOK * 512 * 2;
  bf16* vb  = (bf16*)w; w += (size_t)NTOK * 512 * 2;
  bf16* ab  = hsb;  // alias: hs_bf16 dead after V projection; total ws = 60 MB

  cvt_bf16<<<NTOK * 2048 / 1024, 256, 0, stream>>>(hs, hsb, NTOK * 2048);
  cvt_bf16<<<2048 * 2048 / 1024, 256, 0, stream>>>(Wq, wqb, 2048 * 2048);
  cvt_bf16<<<512 * 2048 / 1024, 256, 0, stream>>>(Wk, wkb, 512 * 2048);
  cvt_bf16<<<512 * 2048 / 1024, 256, 0, stream>>>(Wv, wvb, 512 * 2048);
  cvt_bf16<<<2048 * 2048 / 1024, 256, 0, stream>>>(Wo, wob, 2048 * 2048);

  gemm_bt<bf16><<<dim3(2048 / 128, NTOK / 128), 256, 0, stream>>>(
      hsb, wqb, qb, NTOK, 2048, 2048);
  gemm_bt<bf16><<<dim3(512 / 128, NTOK / 128), 256, 0, stream>>>(
      hsb, wkb, kb, NTOK, 512, 2048);
  gemm_bt<bf16><<<dim3(512 / 128, NTOK / 128), 256, 0, stream>>>(
      hsb, wvb, vb, NTOK, 512, 2048);

  rope_kernel<<<NTOK * NH_Q * 32 / 256, 256, 0, stream>>>(qb, 4, NTOK * NH_Q * 32);
  rope_kernel<<<NTOK * NH_KV * 32 / 256, 256, 0, stream>>>(kb, 2, NTOK * NH_KV * 32);

  attn_kernel<<<dim3(S_LEN / 64, NH_Q, 2), 256, 0, stream>>>(qb, kb, vb, ab);

  gemm_bt<float><<<dim3(2048 / 128, NTOK / 128), 256, 0, stream>>>(
      ab, wob, out, NTOK, 2048, 2048);
}

// Round 2
// 382.898 us; speedup vs baseline: 1.1471x; 1.1471x over previous
//
#include <hip/hip_runtime.h>
#include <cstdint>
#include <cstddef>

typedef __bf16 bf16;
typedef __attribute__((ext_vector_type(8))) __bf16 bf16x8;
typedef __attribute__((ext_vector_type(4))) __bf16 bf16x4;
typedef __attribute__((ext_vector_type(4))) float f32x4;
typedef __attribute__((ext_vector_type(4))) short s16x4;

#define S_LEN   2048
#define WIN     512
#define NH_Q    16
#define NH_KV   4
#define HD_     128
#define NTOK    4096   // B * S

#if defined(__has_builtin)
#if __has_builtin(__builtin_amdgcn_mfma_f32_16x16x16bf16_1k)
#define HAVE_MFMA16 1
#endif
#endif
#ifndef HAVE_MFMA16
#define HAVE_MFMA16 0
#endif

// async global->LDS, 16B per lane; LDS dest = wave-uniform base + lane*16
__device__ __forceinline__ void async_copy16(const void* g, void* l) {
  __builtin_amdgcn_global_load_lds(
      (const __attribute__((address_space(1))) void*)g,
      (__attribute__((address_space(3))) void*)l, 16, 0, 0);
}

// ---------------- fp32 -> bf16 convert ----------------
__global__ __launch_bounds__(256) void cvt_bf16(const float* __restrict__ in,
                                                bf16* __restrict__ out, int n) {
  int i = (blockIdx.x * 256 + threadIdx.x) * 4;
  if (i >= n) return;
  float4 v = *(const float4*)(in + i);
  out[i + 0] = (bf16)v.x;
  out[i + 1] = (bf16)v.y;
  out[i + 2] = (bf16)v.z;
  out[i + 3] = (bf16)v.w;
}

// ---------------- GEMM: C[M][N] = A[M][K] @ W[N][K]^T (m97 structure) -------
template <typename OutT>
__global__ __launch_bounds__(256)
void gemm_bt(const bf16* __restrict__ A, const bf16* __restrict__ W,
             OutT* __restrict__ C, int M, int N, int K) {
  __shared__ __align__(16) bf16 As[128 * 32];
  __shared__ __align__(16) bf16 Bs[128 * 32];
  const int tid  = threadIdx.x;
  const int wave = tid >> 6, lane = tid & 63;
  const int quad = lane >> 4, l16 = lane & 15;
  const int wm = wave >> 1, wn = wave & 1;
  const int m0 = blockIdx.y * 128, n0 = blockIdx.x * 128;
  const int lrow = lane >> 2;
  const int lcol = (lane & 3) * 8;

  f32x4 acc[4][4];
#pragma unroll
  for (int i = 0; i < 4; ++i)
#pragma unroll
    for (int j = 0; j < 4; ++j) acc[i][j] = (f32x4){0.f, 0.f, 0.f, 0.f};

  for (int k0 = 0; k0 < K; k0 += 32) {
    __syncthreads();
#pragma unroll
    for (int it = 0; it < 2; ++it) {
      const int c   = it * 4 + wave;
      const int row = c * 16 + lrow;
      async_copy16(A + (size_t)(m0 + row) * K + k0 + lcol, &As[c * 512]);
      async_copy16(W + (size_t)(n0 + row) * K + k0 + lcol, &Bs[c * 512]);
    }
    __syncthreads();
    bf16x8 af[4], bfr[4];
#pragma unroll
    for (int mt = 0; mt < 4; ++mt)
      af[mt] = *(const bf16x8*)&As[(wm * 64 + mt * 16 + l16) * 32 + quad * 8];
#pragma unroll
    for (int nt = 0; nt < 4; ++nt)
      bfr[nt] = *(const bf16x8*)&Bs[(wn * 64 + nt * 16 + l16) * 32 + quad * 8];
#pragma unroll
    for (int mt = 0; mt < 4; ++mt)
#pragma unroll
      for (int nt = 0; nt < 4; ++nt)
        acc[mt][nt] = __builtin_amdgcn_mfma_f32_16x16x32_bf16(
            af[mt], bfr[nt], acc[mt][nt], 0, 0, 0);
  }
#pragma unroll
  for (int mt = 0; mt < 4; ++mt)
#pragma unroll
    for (int nt = 0; nt < 4; ++nt)
#pragma unroll
      for (int r = 0; r < 4; ++r) {
        const int row = m0 + wm * 64 + mt * 16 + quad * 4 + r;
        const int col = n0 + wn * 64 + nt * 16 + l16;
        C[(size_t)row * N + col] = (OutT)acc[mt][nt][r];
      }
}

// ---------------- partial RoPE (first 64 dims of each head) -----------------
__global__ __launch_bounds__(256)
void rope_kernel(bf16* __restrict__ buf, int nh_shift, int total) {
  int i = blockIdx.x * 256 + threadIdx.x;
  if (i >= total) return;
  int d   = i & 31;
  int t   = i >> 5;
  int h   = t & ((1 << nh_shift) - 1);
  int tok = t >> nh_shift;
  int pos = tok & (S_LEN - 1);
  float invf = exp2f(-(float)d * 0.41524101186091903f);  // 10000^(-d/32)
  float ang  = (float)pos * invf;
  float c = cosf(ang), s = sinf(ang);
  bf16* p = buf + (((size_t)tok << nh_shift) + h) * HD_;
  float x1 = (float)p[d], x2 = (float)p[d + 32];
  p[d]      = (bf16)(x1 * c - x2 * s);
  p[d + 32] = (bf16)(x2 * c + x1 * s);
}

// ---------------- V transpose: vb[tok][kv*128+d] -> vt[b][kv][d][s] ---------
__global__ __launch_bounds__(256)
void transpose_v(const bf16* __restrict__ in, bf16* __restrict__ out) {
  __shared__ bf16 T[64][72];
  const int tid = threadIdx.x;
  const int t0  = blockIdx.x * 64;   // token base (tiles never cross b: 2048%64==0)
  const int dg0 = blockIdx.y * 64;   // global d base (0..511)
#pragma unroll
  for (int it = 0; it < 2; ++it) {
    int idx = tid + it * 256;        // 0..511
    int tl = idx >> 3, dblk = idx & 7;
    bf16x8 v = *(const bf16x8*)(in + (size_t)(t0 + tl) * 512 + dg0 + dblk * 8);
    *(bf16x8*)&T[tl][dblk * 8] = v;  // stride 144B, 16B aligned
  }
  __syncthreads();
  const int b = t0 >> 11, s0 = t0 & (S_LEN - 1);
#pragma unroll
  for (int it = 0; it < 2; ++it) {
    int idx = tid + it * 256;
    int dl = idx >> 3, tblk = idx & 7;
    int dg = dg0 + dl;
    int kvh = dg >> 7, d = dg & 127;
    bf16x8 v;
#pragma unroll
    for (int j = 0; j < 8; ++j) v[j] = T[tblk * 8 + j][dl];
    *(bf16x8*)(out + ((size_t)(b * NH_KV + kvh) * HD_ + d) * S_LEN + s0 + tblk * 8) = v;
  }
}

// ---------------- flash attention, S^T formulation --------------------------
// block = 4 waves, 64 queries (16/wave, query = l16), key tiles of 64.
// S^T = K.Q^T (C-layout: key=quad*4+r, q=l16) -> softmax needs only 2 shfl
// steps; P^T in C-layout IS the B-operand layout of mfma_16x16x16 -> PV with
// no LDS round-trip. O accumulated as O^T, un-transposed via LDS in epilogue.
#define KS_STRIDE 136   // 64 keys x 128 d, +8 pad
#define VT_STRIDE 72    // 128 d x 64 keys, +8 pad

__global__ __launch_bounds__(256)
void attn_kernel(const bf16* __restrict__ Qg, const bf16* __restrict__ Kg,
                 const bf16* __restrict__ Vtg, bf16* __restrict__ Og) {
  __shared__ __align__(16) bf16 Ks[64 * KS_STRIDE];   // K tile [key][d]
  __shared__ __align__(16) bf16 Vt[128 * VT_STRIDE];  // V^T tile [d][key]
#if !HAVE_MFMA16
  __shared__ __align__(16) bf16 Pb[4][16 * 72];       // fallback P buffer
#endif
  const int tid  = threadIdx.x;
  const int wave = tid >> 6, lane = tid & 63;
  const int quad = lane >> 4, l16 = lane & 15;
  const int qt = blockIdx.x, h = blockIdx.y, b = blockIdx.z;
  const int kv = h >> 2;
  const int q0 = qt * 64;
  const int tok0 = b * S_LEN;
  const float scale = 0.08838834764831845f;  // 1/sqrt(128)
  const int q = q0 + wave * 16 + l16;        // this lane's query (s-index)

  // Q fragment (B-operand for S^T = K.Q^T): lane n=l16=q, k=quad*8+j
  bf16x8 qf[4];
  {
    const bf16* qp = Qg + (size_t)(tok0 + q) * (NH_Q * HD_) + h * HD_ + quad * 8;
#pragma unroll
    for (int kb = 0; kb < 4; ++kb) qf[kb] = *(const bf16x8*)(qp + kb * 32);
  }

  f32x4 o[8];
#pragma unroll
  for (int dt = 0; dt < 8; ++dt) o[dt] = (f32x4){0.f, 0.f, 0.f, 0.f};
  float m_run = -__builtin_inff(), l_run = 0.f;

  int kt_begin = q0 - WIN;
  if (kt_begin < 0) kt_begin = 0;
  const int kt_end = q0 + 64;
  const bf16* vt_base = Vtg + (size_t)(b * NH_KV + kv) * HD_ * S_LEN;

  for (int kt = kt_begin; kt < kt_end; kt += 64) {
    __syncthreads();
    // stage K [64 key][128 d] padded, b128 writes
#pragma unroll
    for (int it = 0; it < 4; ++it) {
      int vid = tid + it * 256;        // 0..1023
      int key = vid >> 4, dblk = vid & 15;
      bf16x8 v = *(const bf16x8*)(Kg + (size_t)(tok0 + kt + key) * (NH_KV * HD_)
                                  + kv * HD_ + dblk * 8);
      *(bf16x8*)&Ks[key * KS_STRIDE + dblk * 8] = v;
    }
    // stage V^T [128 d][64 key] padded, b128 writes (from pre-transposed global)
#pragma unroll
    for (int it = 0; it < 4; ++it) {
      int vid = tid + it * 256;
      int d = vid >> 3, kblk = vid & 7;
      bf16x8 v = *(const bf16x8*)(vt_base + (size_t)d * S_LEN + kt + kblk * 8);
      *(bf16x8*)&Vt[d * VT_STRIDE + kblk * 8] = v;
    }
    __syncthreads();

    // S^T[key][q] = K.Q^T : A-frag = K rows (m=key=l16), B-frag = qf
    f32x4 st[4];
#pragma unroll
    for (int nt = 0; nt < 4; ++nt) {
      f32x4 acc = (f32x4){0.f, 0.f, 0.f, 0.f};
#pragma unroll
      for (int kb = 0; kb < 4; ++kb) {
        bf16x8 kf = *(const bf16x8*)&Ks[(nt * 16 + l16) * KS_STRIDE + kb * 32 + quad * 8];
        acc = __builtin_amdgcn_mfma_f32_16x16x32_bf16(kf, qf[kb], acc, 0, 0, 0);
      }
      st[nt] = acc;
    }
    // mask + scale: key = kt + nt*16 + quad*4 + r, query = q (per lane)
#pragma unroll
    for (int nt = 0; nt < 4; ++nt)
#pragma unroll
      for (int r = 0; r < 4; ++r) {
        int key = kt + nt * 16 + quad * 4 + r;
        bool ok = (key <= q) && (key > q - WIN);
        st[nt][r] = ok ? st[nt][r] * scale : -__builtin_inff();
      }
    // online softmax: 16 in-reg values per lane + butterfly over quads (16,32)
    float mx = -__builtin_inff();
#pragma unroll
    for (int nt = 0; nt < 4; ++nt)
#pragma unroll
      for (int r = 0; r < 4; ++r) mx = fmaxf(mx, st[nt][r]);
    mx = fmaxf(mx, __shfl_xor(mx, 16, 64));
    mx = fmaxf(mx, __shfl_xor(mx, 32, 64));
    float mnew = fmaxf(m_run, mx);
    float msub = (mnew == -__builtin_inff()) ? 0.f : mnew;  // NaN guard
    float alpha = __expf(m_run - msub);
    m_run = mnew;
    float p[4][4], psum = 0.f;
#pragma unroll
    for (int nt = 0; nt < 4; ++nt)
#pragma unroll
      for (int r = 0; r < 4; ++r) {
        p[nt][r] = __expf(st[nt][r] - msub);
        psum += p[nt][r];
      }
    psum += __shfl_xor(psum, 16, 64);
    psum += __shfl_xor(psum, 32, 64);
    l_run = l_run * alpha + psum;
#pragma unroll
    for (int dt = 0; dt < 8; ++dt) o[dt] *= alpha;  // one query per lane

#if HAVE_MFMA16
    // P^T C-layout (key=quad*4+r) == B-operand of 16x16x16 (k=quad*4+j):
    // PV straight from registers, no LDS round-trip.
    s16x4 pb[4];
#pragma unroll
    for (int nt = 0; nt < 4; ++nt)
#pragma unroll
      for (int r = 0; r < 4; ++r) {
        union { __bf16 h; short s; } u;
        u.h = (bf16)p[nt][r];
        pb[nt][r] = u.s;
      }
#pragma unroll
    for (int dt = 0; dt < 8; ++dt)
#pragma unroll
      for (int nt = 0; nt < 4; ++nt) {
        s16x4 vf = *(const s16x4*)&Vt[(dt * 16 + l16) * VT_STRIDE + nt * 16 + quad * 4];
        o[dt] = __builtin_amdgcn_mfma_f32_16x16x16bf16_1k(vf, pb[nt], o[dt], 0, 0, 0);
      }
#else
    // fallback: P^T -> LDS [q][key] rows, read back as 16x16x32 B-frags
#pragma unroll
    for (int nt = 0; nt < 4; ++nt) {
      bf16x4 t;
#pragma unroll
      for (int r = 0; r < 4; ++r) t[r] = (bf16)p[nt][r];
      *(bf16x4*)&Pb[wave][l16 * 72 + nt * 16 + quad * 4] = t;
    }
    __syncthreads();
    bf16x8 pf[2];
    pf[0] = *(const bf16x8*)&Pb[wave][l16 * 72 + quad * 8];
    pf[1] = *(const bf16x8*)&Pb[wave][l16 * 72 + 32 + quad * 8];
#pragma unroll
    for (int dt = 0; dt < 8; ++dt)
#pragma unroll
      for (int kb = 0; kb < 2; ++kb) {
        bf16x8 vf = *(const bf16x8*)&Vt[(dt * 16 + l16) * VT_STRIDE + kb * 32 + quad * 8];
        o[dt] = __builtin_amdgcn_mfma_f32_16x16x32_bf16(vf, pf[kb], o[dt], 0, 0, 0);
      }
#endif
  }

  // epilogue: O^T (d=dt*16+quad*4+r, q=l16) -> LDS [q][d] -> coalesced stores
  float inv = 1.f / l_run;
  __syncthreads();  // all waves done with Ks
#pragma unroll
  for (int dt = 0; dt < 8; ++dt) {
    bf16x4 t;
#pragma unroll
    for (int r = 0; r < 4; ++r) t[r] = (bf16)(o[dt][r] * inv);
    *(bf16x4*)&Ks[(wave * 16 + l16) * KS_STRIDE + dt * 16 + quad * 4] = t;
  }
  __syncthreads();
#pragma unroll
  for (int it = 0; it < 4; ++it) {
    int idx = tid + it * 256;          // 0..1023
    int row = idx >> 4, chunk = idx & 15;
    bf16x8 v = *(const bf16x8*)&Ks[row * KS_STRIDE + chunk * 8];
    *(bf16x8*)(Og + (size_t)(tok0 + q0 + row) * (NH_Q * HD_) + h * HD_ + chunk * 8) = v;
  }
}

// ---------------- launcher ----------------
extern "C" void kernel_launch(void* const* d_in, const int* in_sizes, int n_in,
                              void* d_out, int out_size, void* d_ws, size_t ws_size,
                              hipStream_t stream) {
  const float* hs = (const float*)d_in[0];
  const float* Wq = (const float*)d_in[1];
  const float* Wk = (const float*)d_in[2];
  const float* Wv = (const float*)d_in[3];
  const float* Wo = (const float*)d_in[4];
  float* out = (float*)d_out;

  char* w = (char*)d_ws;
  bf16* hsb = (bf16*)w; w += (size_t)NTOK * 2048 * 2;
  bf16* wqb = (bf16*)w; w += (size_t)2048 * 2048 * 2;
  bf16* wkb = (bf16*)w; w += (size_t)512 * 2048 * 2;
  bf16* wvb = (bf16*)w; w += (size_t)512 * 2048 * 2;
  bf16* wob = (bf16*)w; w += (size_t)2048 * 2048 * 2;
  bf16* qb  = (bf16*)w; w += (size_t)NTOK * 2048 * 2;
  bf16* kb  = (bf16*)w; w += (size_t)NTOK * 512 * 2;
  bf16* vb  = (bf16*)w; w += (size_t)NTOK * 512 * 2;
  bf16* ab  = hsb;   // alias: hs_bf16 dead after V projection
  bf16* vtb = wkb;   // alias: wkb+wvb (4MB) dead after K/V GEMMs

  cvt_bf16<<<NTOK * 2048 / 1024, 256, 0, stream>>>(hs, hsb, NTOK * 2048);
  cvt_bf16<<<2048 * 2048 / 1024, 256, 0, stream>>>(Wq, wqb, 2048 * 2048);
  cvt_bf16<<<512 * 2048 / 1024, 256, 0, stream>>>(Wk, wkb, 512 * 2048);
  cvt_bf16<<<512 * 2048 / 1024, 256, 0, stream>>>(Wv, wvb, 512 * 2048);
  cvt_bf16<<<2048 * 2048 / 1024, 256, 0, stream>>>(Wo, wob, 2048 * 2048);

  gemm_bt<bf16><<<dim3(2048 / 128, NTOK / 128), 256, 0, stream>>>(
      hsb, wqb, qb, NTOK, 2048, 2048);
  gemm_bt<bf16><<<dim3(512 / 128, NTOK / 128), 256, 0, stream>>>(
      hsb, wkb, kb, NTOK, 512, 2048);
  gemm_bt<bf16><<<dim3(512 / 128, NTOK / 128), 256, 0, stream>>>(
      hsb, wvb, vb, NTOK, 512, 2048);

  rope_kernel<<<NTOK * NH_Q * 32 / 256, 256, 0, stream>>>(qb, 4, NTOK * NH_Q * 32);
  rope_kernel<<<NTOK * NH_KV * 32 / 256, 256, 0, stream>>>(kb, 2, NTOK * NH_KV * 32);

  transpose_v<<<dim3(NTOK / 64, 512 / 64), 256, 0, stream>>>(vb, vtb);

  attn_kernel<<<dim3(S_LEN / 64, NH_Q, 2), 256, 0, stream>>>(qb, kb, vtb, ab);

  gemm_bt<float><<<dim3(2048 / 128, NTOK / 128), 256, 0, stream>>>(
      ab, wob, out, NTOK, 2048, 2048);
}

// Round 3
// 311.839 us; speedup vs baseline: 1.4085x; 1.2279x over previous
//
#include <hip/hip_runtime.h>
#include <cstdint>
#include <cstddef>

typedef __bf16 bf16;
typedef __attribute__((ext_vector_type(8))) __bf16 bf16x8;
typedef __attribute__((ext_vector_type(4))) __bf16 bf16x4;
typedef __attribute__((ext_vector_type(4))) float f32x4;
typedef __attribute__((ext_vector_type(4))) short s16x4;

#define S_LEN   2048
#define WIN     512
#define NH_Q    16
#define NH_KV   4
#define HD_     128
#define NTOK    4096   // B * S

#if defined(__has_builtin)
#if __has_builtin(__builtin_amdgcn_mfma_f32_16x16x16bf16_1k)
#define HAVE_MFMA16 1
#endif
#endif
#ifndef HAVE_MFMA16
#define HAVE_MFMA16 0
#endif

// async global->LDS, 16B per lane; LDS dest = wave-uniform base + lane*16
__device__ __forceinline__ void async_copy16(const void* g, void* l) {
  __builtin_amdgcn_global_load_lds(
      (const __attribute__((address_space(1))) void*)g,
      (__attribute__((address_space(3))) void*)l, 16, 0, 0);
}

// ---------------- fp32 -> bf16 convert, all 5 arrays in one launch ----------
// segments: hs 8388608 | Wq 4194304 | Wk 1048576 | Wv 1048576 | Wo 4194304
__global__ __launch_bounds__(256)
void cvt_all(const float* __restrict__ hs, const float* __restrict__ wq,
             const float* __restrict__ wk, const float* __restrict__ wv,
             const float* __restrict__ wo, bf16* __restrict__ hsb,
             bf16* __restrict__ wqb, bf16* __restrict__ wkb,
             bf16* __restrict__ wvb, bf16* __restrict__ wob) {
  long i = ((long)blockIdx.x * 256 + threadIdx.x) * 4;  // < 18874368
  const float* in;
  bf16* out;
  if (i < 8388608)       { in = hs + i;            out = hsb + i; }
  else if (i < 12582912) { in = wq + (i - 8388608); out = wqb + (i - 8388608); }
  else if (i < 13631488) { in = wk + (i - 12582912); out = wkb + (i - 12582912); }
  else if (i < 14680064) { in = wv + (i - 13631488); out = wvb + (i - 13631488); }
  else                   { in = wo + (i - 14680064); out = wob + (i - 14680064); }
  float4 v = *(const float4*)in;
  bf16x4 t = {(bf16)v.x, (bf16)v.y, (bf16)v.z, (bf16)v.w};
  *(bf16x4*)out = t;
}

// ---------------- GEMM: C[M][N] = A[M][K] @ W[N][K]^T (m97 structure) -------
template <typename OutT>
__global__ __launch_bounds__(256)
void gemm_bt(const bf16* __restrict__ A, const bf16* __restrict__ W,
             OutT* __restrict__ C, int M, int N, int K) {
  __shared__ __align__(16) bf16 As[128 * 32];
  __shared__ __align__(16) bf16 Bs[128 * 32];
  const int tid  = threadIdx.x;
  const int wave = tid >> 6, lane = tid & 63;
  const int quad = lane >> 4, l16 = lane & 15;
  const int wm = wave >> 1, wn = wave & 1;
  const int m0 = blockIdx.y * 128, n0 = blockIdx.x * 128;
  const int lrow = lane >> 2;
  const int lcol = (lane & 3) * 8;

  f32x4 acc[4][4];
#pragma unroll
  for (int i = 0; i < 4; ++i)
#pragma unroll
    for (int j = 0; j < 4; ++j) acc[i][j] = (f32x4){0.f, 0.f, 0.f, 0.f};

  for (int k0 = 0; k0 < K; k0 += 32) {
    __syncthreads();
#pragma unroll
    for (int it = 0; it < 2; ++it) {
      const int c   = it * 4 + wave;
      const int row = c * 16 + lrow;
      async_copy16(A + (size_t)(m0 + row) * K + k0 + lcol, &As[c * 512]);
      async_copy16(W + (size_t)(n0 + row) * K + k0 + lcol, &Bs[c * 512]);
    }
    __syncthreads();
    bf16x8 af[4], bfr[4];
#pragma unroll
    for (int mt = 0; mt < 4; ++mt)
      af[mt] = *(const bf16x8*)&As[(wm * 64 + mt * 16 + l16) * 32 + quad * 8];
#pragma unroll
    for (int nt = 0; nt < 4; ++nt)
      bfr[nt] = *(const bf16x8*)&Bs[(wn * 64 + nt * 16 + l16) * 32 + quad * 8];
#pragma unroll
    for (int mt = 0; mt < 4; ++mt)
#pragma unroll
      for (int nt = 0; nt < 4; ++nt)
        acc[mt][nt] = __builtin_amdgcn_mfma_f32_16x16x32_bf16(
            af[mt], bfr[nt], acc[mt][nt], 0, 0, 0);
  }
#pragma unroll
  for (int mt = 0; mt < 4; ++mt)
#pragma unroll
    for (int nt = 0; nt < 4; ++nt)
#pragma unroll
      for (int r = 0; r < 4; ++r) {
        const int row = m0 + wm * 64 + mt * 16 + quad * 4 + r;
        const int col = n0 + wn * 64 + nt * 16 + l16;
        C[(size_t)row * N + col] = (OutT)acc[mt][nt][r];
      }
}

// ---------------- fused QKV GEMM + RoPE + V-transpose -----------------------
// grid.x = 24: bx 0..15 -> Q (N=2048), 16..19 -> K (N=512), 20..23 -> V.
// RoPE fused in-register: pair (d, d+32) = acc[mt][nt] / acc[mt][nt+2] on
// wn==0 waves (col%128 = wn*64+nt*16+l16; d<32 <=> wn==0, nt<2).
// V written directly transposed to vt[b][kv][d][s].
__global__ __launch_bounds__(256)
void gemm_qkv(const bf16* __restrict__ A, const bf16* __restrict__ Wq,
              const bf16* __restrict__ Wk, const bf16* __restrict__ Wv,
              bf16* __restrict__ Qo, bf16* __restrict__ Ko,
              bf16* __restrict__ Vt) {
  __shared__ __align__(16) bf16 As[128 * 32];
  __shared__ __align__(16) bf16 Bs[128 * 32];
  const int tid  = threadIdx.x;
  const int wave = tid >> 6, lane = tid & 63;
  const int quad = lane >> 4, l16 = lane & 15;
  const int wm = wave >> 1, wn = wave & 1;
  const int bx = blockIdx.x;
  const int m0 = blockIdx.y * 128;
  const int region = (bx < 16) ? 0 : (bx < 20 ? 1 : 2);
  const bf16* W = (region == 0) ? Wq + (size_t)bx * 128 * 2048
                : (region == 1) ? Wk + (size_t)(bx - 16) * 128 * 2048
                                : Wv + (size_t)(bx - 20) * 128 * 2048;
  const int lrow = lane >> 2;
  const int lcol = (lane & 3) * 8;

  f32x4 acc[4][4];
#pragma unroll
  for (int i = 0; i < 4; ++i)
#pragma unroll
    for (int j = 0; j < 4; ++j) acc[i][j] = (f32x4){0.f, 0.f, 0.f, 0.f};

  for (int k0 = 0; k0 < 2048; k0 += 32) {
    __syncthreads();
#pragma unroll
    for (int it = 0; it < 2; ++it) {
      const int c   = it * 4 + wave;
      const int row = c * 16 + lrow;
      async_copy16(A + (size_t)(m0 + row) * 2048 + k0 + lcol, &As[c * 512]);
      async_copy16(W + (size_t)row * 2048 + k0 + lcol, &Bs[c * 512]);
    }
    __syncthreads();
    bf16x8 af[4], bfr[4];
#pragma unroll
    for (int mt = 0; mt < 4; ++mt)
      af[mt] = *(const bf16x8*)&As[(wm * 64 + mt * 16 + l16) * 32 + quad * 8];
#pragma unroll
    for (int nt = 0; nt < 4; ++nt)
      bfr[nt] = *(const bf16x8*)&Bs[(wn * 64 + nt * 16 + l16) * 32 + quad * 8];
#pragma unroll
    for (int mt = 0; mt < 4; ++mt)
#pragma unroll
      for (int nt = 0; nt < 4; ++nt)
        acc[mt][nt] = __builtin_amdgcn_mfma_f32_16x16x32_bf16(
            af[mt], bfr[nt], acc[mt][nt], 0, 0, 0);
  }

  // fused RoPE (Q and K regions, wn==0 waves only; wave-uniform branch)
  if (region < 2 && wn == 0) {
#pragma unroll
    for (int nt = 0; nt < 2; ++nt) {
      const int d = nt * 16 + l16;  // 0..31
      const float invf = exp2f(-(float)d * 0.41524101186091903f);  // 10000^(-d/32)
#pragma unroll
      for (int mt = 0; mt < 4; ++mt)
#pragma unroll
        for (int r = 0; r < 4; ++r) {
          const int pos = (m0 + wm * 64 + mt * 16 + quad * 4 + r) & (S_LEN - 1);
          float s, c;
          __sincosf((float)pos * invf, &s, &c);
          const float x1 = acc[mt][nt][r], x2 = acc[mt][nt + 2][r];
          acc[mt][nt][r]     = x1 * c - x2 * s;
          acc[mt][nt + 2][r] = x2 * c + x1 * s;
        }
    }
  }

  if (region == 0) {  // Q: [tok][2048]
#pragma unroll
    for (int mt = 0; mt < 4; ++mt)
#pragma unroll
      for (int nt = 0; nt < 4; ++nt)
#pragma unroll
        for (int r = 0; r < 4; ++r) {
          const int row = m0 + wm * 64 + mt * 16 + quad * 4 + r;
          const int col = bx * 128 + wn * 64 + nt * 16 + l16;
          Qo[(size_t)row * 2048 + col] = (bf16)acc[mt][nt][r];
        }
  } else if (region == 1) {  // K: [tok][512]
#pragma unroll
    for (int mt = 0; mt < 4; ++mt)
#pragma unroll
      for (int nt = 0; nt < 4; ++nt)
#pragma unroll
        for (int r = 0; r < 4; ++r) {
          const int row = m0 + wm * 64 + mt * 16 + quad * 4 + r;
          const int col = (bx - 16) * 128 + wn * 64 + nt * 16 + l16;
          Ko[(size_t)row * 512 + col] = (bf16)acc[mt][nt][r];
        }
  } else {  // V: transposed -> vt[(b*4+kv)*128 + d][s]; 4 consecutive s/lane
#pragma unroll
    for (int mt = 0; mt < 4; ++mt) {
      const int row0 = m0 + wm * 64 + mt * 16 + quad * 4;
      const int b = row0 >> 11, s0 = row0 & (S_LEN - 1);
#pragma unroll
      for (int nt = 0; nt < 4; ++nt) {
        const int colv = (bx - 20) * 128 + wn * 64 + nt * 16 + l16;  // 0..511
        const int kvh = colv >> 7, d = colv & 127;
        bf16x4 t = {(bf16)acc[mt][nt][0], (bf16)acc[mt][nt][1],
                    (bf16)acc[mt][nt][2], (bf16)acc[mt][nt][3]};
        *(bf16x4*)(Vt + ((size_t)(b * NH_KV + kvh) * HD_ + d) * S_LEN + s0) = t;
      }
    }
  }
}

// ---------------- flash attention, S^T formulation --------------------------
#define KS_STRIDE 136   // 64 keys x 128 d, +8 pad
#define VT_STRIDE 72    // 128 d x 64 keys, +8 pad

__global__ __launch_bounds__(256)
void attn_kernel(const bf16* __restrict__ Qg, const bf16* __restrict__ Kg,
                 const bf16* __restrict__ Vtg, bf16* __restrict__ Og) {
  __shared__ __align__(16) bf16 Ks[64 * KS_STRIDE];   // K tile [key][d]
  __shared__ __align__(16) bf16 Vt[128 * VT_STRIDE];  // V^T tile [d][key]
#if !HAVE_MFMA16
  __shared__ __align__(16) bf16 Pb[4][16 * 72];
#endif
  const int tid  = threadIdx.x;
  const int wave = tid >> 6, lane = tid & 63;
  const int quad = lane >> 4, l16 = lane & 15;
  const int qt = blockIdx.x, h = blockIdx.y, b = blockIdx.z;
  const int kv = h >> 2;
  const int q0 = qt * 64;
  const int tok0 = b * S_LEN;
  const float scale = 0.08838834764831845f;  // 1/sqrt(128)
  const int q = q0 + wave * 16 + l16;

  bf16x8 qf[4];
  {
    const bf16* qp = Qg + (size_t)(tok0 + q) * (NH_Q * HD_) + h * HD_ + quad * 8;
#pragma unroll
    for (int kb = 0; kb < 4; ++kb) qf[kb] = *(const bf16x8*)(qp + kb * 32);
  }

  f32x4 o[8];
#pragma unroll
  for (int dt = 0; dt < 8; ++dt) o[dt] = (f32x4){0.f, 0.f, 0.f, 0.f};
  float m_run = -__builtin_inff(), l_run = 0.f;

  int kt_begin = q0 - WIN;
  if (kt_begin < 0) kt_begin = 0;
  const int kt_end = q0 + 64;
  const bf16* vt_base = Vtg + (size_t)(b * NH_KV + kv) * HD_ * S_LEN;

  for (int kt = kt_begin; kt < kt_end; kt += 64) {
    __syncthreads();
#pragma unroll
    for (int it = 0; it < 4; ++it) {
      int vid = tid + it * 256;
      int key = vid >> 4, dblk = vid & 15;
      bf16x8 v = *(const bf16x8*)(Kg + (size_t)(tok0 + kt + key) * (NH_KV * HD_)
                                  + kv * HD_ + dblk * 8);
      *(bf16x8*)&Ks[key * KS_STRIDE + dblk * 8] = v;
    }
#pragma unroll
    for (int it = 0; it < 4; ++it) {
      int vid = tid + it * 256;
      int d = vid >> 3, kblk = vid & 7;
      bf16x8 v = *(const bf16x8*)(vt_base + (size_t)d * S_LEN + kt + kblk * 8);
      *(bf16x8*)&Vt[d * VT_STRIDE + kblk * 8] = v;
    }
    __syncthreads();

    f32x4 st[4];
#pragma unroll
    for (int nt = 0; nt < 4; ++nt) {
      f32x4 acc = (f32x4){0.f, 0.f, 0.f, 0.f};
#pragma unroll
      for (int kb = 0; kb < 4; ++kb) {
        bf16x8 kf = *(const bf16x8*)&Ks[(nt * 16 + l16) * KS_STRIDE + kb * 32 + quad * 8];
        acc = __builtin_amdgcn_mfma_f32_16x16x32_bf16(kf, qf[kb], acc, 0, 0, 0);
      }
      st[nt] = acc;
    }
#pragma unroll
    for (int nt = 0; nt < 4; ++nt)
#pragma unroll
      for (int r = 0; r < 4; ++r) {
        int key = kt + nt * 16 + quad * 4 + r;
        bool ok = (key <= q) && (key > q - WIN);
        st[nt][r] = ok ? st[nt][r] * scale : -__builtin_inff();
      }
    float mx = -__builtin_inff();
#pragma unroll
    for (int nt = 0; nt < 4; ++nt)
#pragma unroll
      for (int r = 0; r < 4; ++r) mx = fmaxf(mx, st[nt][r]);
    mx = fmaxf(mx, __shfl_xor(mx, 16, 64));
    mx = fmaxf(mx, __shfl_xor(mx, 32, 64));
    float mnew = fmaxf(m_run, mx);
    float msub = (mnew == -__builtin_inff()) ? 0.f : mnew;
    float alpha = __expf(m_run - msub);
    m_run = mnew;
    float p[4][4], psum = 0.f;
#pragma unroll
    for (int nt = 0; nt < 4; ++nt)
#pragma unroll
      for (int r = 0; r < 4; ++r) {
        p[nt][r] = __expf(st[nt][r] - msub);
        psum += p[nt][r];
      }
    psum += __shfl_xor(psum, 16, 64);
    psum += __shfl_xor(psum, 32, 64);
    l_run = l_run * alpha + psum;
#pragma unroll
    for (int dt = 0; dt < 8; ++dt) o[dt] *= alpha;

#if HAVE_MFMA16
    s16x4 pb[4];
#pragma unroll
    for (int nt = 0; nt < 4; ++nt)
#pragma unroll
      for (int r = 0; r < 4; ++r) {
        union { __bf16 h; short s; } u;
        u.h = (bf16)p[nt][r];
        pb[nt][r] = u.s;
      }
#pragma unroll
    for (int dt = 0; dt < 8; ++dt)
#pragma unroll
      for (int nt = 0; nt < 4; ++nt) {
        s16x4 vf = *(const s16x4*)&Vt[(dt * 16 + l16) * VT_STRIDE + nt * 16 + quad * 4];
        o[dt] = __builtin_amdgcn_mfma_f32_16x16x16bf16_1k(vf, pb[nt], o[dt], 0, 0, 0);
      }
#else
#pragma unroll
    for (int nt = 0; nt < 4; ++nt) {
      bf16x4 t;
#pragma unroll
      for (int r = 0; r < 4; ++r) t[r] = (bf16)p[nt][r];
      *(bf16x4*)&Pb[wave][l16 * 72 + nt * 16 + quad * 4] = t;
    }
    __syncthreads();
    bf16x8 pf[2];
    pf[0] = *(const bf16x8*)&Pb[wave][l16 * 72 + quad * 8];
    pf[1] = *(const bf16x8*)&Pb[wave][l16 * 72 + 32 + quad * 8];
#pragma unroll
    for (int dt = 0; dt < 8; ++dt)
#pragma unroll
      for (int kb = 0; kb < 2; ++kb) {
        bf16x8 vf = *(const bf16x8*)&Vt[(dt * 16 + l16) * VT_STRIDE + kb * 32 + quad * 8];
        o[dt] = __builtin_amdgcn_mfma_f32_16x16x32_bf16(vf, pf[kb], o[dt], 0, 0, 0);
      }
#endif
  }

  float inv = 1.f / l_run;
  __syncthreads();
#pragma unroll
  for (int dt = 0; dt < 8; ++dt) {
    bf16x4 t;
#pragma unroll
    for (int r = 0; r < 4; ++r) t[r] = (bf16)(o[dt][r] * inv);
    *(bf16x4*)&Ks[(wave * 16 + l16) * KS_STRIDE + dt * 16 + quad * 4] = t;
  }
  __syncthreads();
#pragma unroll
  for (int it = 0; it < 4; ++it) {
    int idx = tid + it * 256;
    int row = idx >> 4, chunk = idx & 15;
    bf16x8 v = *(const bf16x8*)&Ks[row * KS_STRIDE + chunk * 8];
    *(bf16x8*)(Og + (size_t)(tok0 + q0 + row) * (NH_Q * HD_) + h * HD_ + chunk * 8) = v;
  }
}

// ---------------- launcher ----------------
extern "C" void kernel_launch(void* const* d_in, const int* in_sizes, int n_in,
                              void* d_out, int out_size, void* d_ws, size_t ws_size,
                              hipStream_t stream) {
  const float* hs = (const float*)d_in[0];
  const float* Wq = (const float*)d_in[1];
  const float* Wk = (const float*)d_in[2];
  const float* Wv = (const float*)d_in[3];
  const float* Wo = (const float*)d_in[4];
  float* out = (float*)d_out;

  char* w = (char*)d_ws;
  bf16* hsb = (bf16*)w; w += (size_t)NTOK * 2048 * 2;   // 16.8 MB
  bf16* wqb = (bf16*)w; w += (size_t)2048 * 2048 * 2;   //  8.4 MB
  bf16* wkb = (bf16*)w; w += (size_t)512 * 2048 * 2;    //  2.1 MB
  bf16* wvb = (bf16*)w; w += (size_t)512 * 2048 * 2;    //  2.1 MB
  bf16* wob = (bf16*)w; w += (size_t)2048 * 2048 * 2;   //  8.4 MB
  bf16* qb  = (bf16*)w; w += (size_t)NTOK * 2048 * 2;   // 16.8 MB
  bf16* kb  = (bf16*)w; w += (size_t)NTOK * 512 * 2;    //  4.2 MB
  bf16* vtb = (bf16*)w; w += (size_t)NTOK * 512 * 2;    //  4.2 MB (own slice!)
  bf16* ab  = hsb;  // alias: hs_bf16 dead after QKV GEMM

  cvt_all<<<18874368 / 1024, 256, 0, stream>>>(hs, Wq, Wk, Wv, Wo,
                                               hsb, wqb, wkb, wvb, wob);

  gemm_qkv<<<dim3(24, NTOK / 128), 256, 0, stream>>>(hsb, wqb, wkb, wvb,
                                                     qb, kb, vtb);

  attn_kernel<<<dim3(S_LEN / 64, NH_Q, 2), 256, 0, stream>>>(qb, kb, vtb, ab);

  gemm_bt<float><<<dim3(2048 / 128, NTOK / 128), 256, 0, stream>>>(
      ab, wob, out, NTOK, 2048, 2048);
}

// Round 4
// 303.491 us; speedup vs baseline: 1.4473x; 1.0275x over previous
//
#include <hip/hip_runtime.h>
#include <cstdint>
#include <cstddef>

typedef __bf16 bf16;
typedef __attribute__((ext_vector_type(8))) __bf16 bf16x8;
typedef __attribute__((ext_vector_type(4))) __bf16 bf16x4;
typedef __attribute__((ext_vector_type(4))) float f32x4;
typedef __attribute__((ext_vector_type(4))) short s16x4;

#define S_LEN   2048
#define WIN     512
#define NH_Q    16
#define NH_KV   4
#define HD_     128
#define NTOK    4096   // B * S

#if defined(__has_builtin)
#if __has_builtin(__builtin_amdgcn_mfma_f32_16x16x16bf16_1k)
#define HAVE_MFMA16 1
#endif
#endif
#ifndef HAVE_MFMA16
#define HAVE_MFMA16 0
#endif

// async global->LDS, 16B per lane; LDS dest = wave-uniform base + lane*16
__device__ __forceinline__ void async_copy16(const void* g, void* l) {
  __builtin_amdgcn_global_load_lds(
      (const __attribute__((address_space(1))) void*)g,
      (__attribute__((address_space(3))) void*)l, 16, 0, 0);
}

// ---------------- fp32 -> bf16 convert, all 5 arrays in one launch ----------
__global__ __launch_bounds__(256)
void cvt_all(const float* __restrict__ hs, const float* __restrict__ wq,
             const float* __restrict__ wk, const float* __restrict__ wv,
             const float* __restrict__ wo, bf16* __restrict__ hsb,
             bf16* __restrict__ wqb, bf16* __restrict__ wkb,
             bf16* __restrict__ wvb, bf16* __restrict__ wob) {
  long i = ((long)blockIdx.x * 256 + threadIdx.x) * 4;  // < 18874368
  const float* in;
  bf16* out;
  if (i < 8388608)       { in = hs + i;            out = hsb + i; }
  else if (i < 12582912) { in = wq + (i - 8388608); out = wqb + (i - 8388608); }
  else if (i < 13631488) { in = wk + (i - 12582912); out = wkb + (i - 12582912); }
  else if (i < 14680064) { in = wv + (i - 13631488); out = wvb + (i - 13631488); }
  else                   { in = wo + (i - 14680064); out = wob + (i - 14680064); }
  float4 v = *(const float4*)in;
  bf16x4 t = {(bf16)v.x, (bf16)v.y, (bf16)v.z, (bf16)v.w};
  *(bf16x4*)out = t;
}

// ---------------- GEMM: C[M][N] = A[M][K] @ W[N][K]^T -----------------------
// m97 structure + double-buffered LDS: stage tile k+1 while computing tile k
// so the per-barrier vmcnt(0) drain has a full compute phase of slack.
// Matters here because grids are 512-768 blocks = 2-3 blocks/CU (low TLP).
template <typename OutT>
__global__ __launch_bounds__(256)
void gemm_bt(const bf16* __restrict__ A, const bf16* __restrict__ W,
             OutT* __restrict__ C, int M, int N, int K) {
  __shared__ __align__(16) bf16 As[2][128 * 32];
  __shared__ __align__(16) bf16 Bs[2][128 * 32];
  const int tid  = threadIdx.x;
  const int wave = tid >> 6, lane = tid & 63;
  const int quad = lane >> 4, l16 = lane & 15;
  const int wm = wave >> 1, wn = wave & 1;
  const int m0 = blockIdx.y * 128, n0 = blockIdx.x * 128;
  const int lrow = lane >> 2;
  const int lcol = (lane & 3) * 8;

  f32x4 acc[4][4];
#pragma unroll
  for (int i = 0; i < 4; ++i)
#pragma unroll
    for (int j = 0; j < 4; ++j) acc[i][j] = (f32x4){0.f, 0.f, 0.f, 0.f};

  auto stage = [&](int buf, int k0) {
#pragma unroll
    for (int it = 0; it < 2; ++it) {
      const int c   = it * 4 + wave;
      const int row = c * 16 + lrow;
      async_copy16(A + (size_t)(m0 + row) * K + k0 + lcol, &As[buf][c * 512]);
      async_copy16(W + (size_t)(n0 + row) * K + k0 + lcol, &Bs[buf][c * 512]);
    }
  };

  stage(0, 0);
  __syncthreads();  // vmcnt(0): tile 0 resident
  for (int k0 = 0; k0 < K; k0 += 32) {
    const int cur = (k0 >> 5) & 1;
    if (k0 + 32 < K) stage(cur ^ 1, k0 + 32);  // prefetch next, no wait
    bf16x8 af[4], bfr[4];
#pragma unroll
    for (int mt = 0; mt < 4; ++mt)
      af[mt] = *(const bf16x8*)&As[cur][(wm * 64 + mt * 16 + l16) * 32 + quad * 8];
#pragma unroll
    for (int nt = 0; nt < 4; ++nt)
      bfr[nt] = *(const bf16x8*)&Bs[cur][(wn * 64 + nt * 16 + l16) * 32 + quad * 8];
#pragma unroll
    for (int mt = 0; mt < 4; ++mt)
#pragma unroll
      for (int nt = 0; nt < 4; ++nt)
        acc[mt][nt] = __builtin_amdgcn_mfma_f32_16x16x32_bf16(
            af[mt], bfr[nt], acc[mt][nt], 0, 0, 0);
    __syncthreads();  // next tile staged + this buffer free for k0+64 rewrite
  }
#pragma unroll
  for (int mt = 0; mt < 4; ++mt)
#pragma unroll
    for (int nt = 0; nt < 4; ++nt)
#pragma unroll
      for (int r = 0; r < 4; ++r) {
        const int row = m0 + wm * 64 + mt * 16 + quad * 4 + r;
        const int col = n0 + wn * 64 + nt * 16 + l16;
        C[(size_t)row * N + col] = (OutT)acc[mt][nt][r];
      }
}

// ---------------- fused QKV GEMM + RoPE + V-transpose (double-buffered) -----
__global__ __launch_bounds__(256)
void gemm_qkv(const bf16* __restrict__ A, const bf16* __restrict__ Wq,
              const bf16* __restrict__ Wk, const bf16* __restrict__ Wv,
              bf16* __restrict__ Qo, bf16* __restrict__ Ko,
              bf16* __restrict__ Vt) {
  __shared__ __align__(16) bf16 As[2][128 * 32];
  __shared__ __align__(16) bf16 Bs[2][128 * 32];
  const int tid  = threadIdx.x;
  const int wave = tid >> 6, lane = tid & 63;
  const int quad = lane >> 4, l16 = lane & 15;
  const int wm = wave >> 1, wn = wave & 1;
  const int bx = blockIdx.x;
  const int m0 = blockIdx.y * 128;
  const int region = (bx < 16) ? 0 : (bx < 20 ? 1 : 2);
  const bf16* W = (region == 0) ? Wq + (size_t)bx * 128 * 2048
                : (region == 1) ? Wk + (size_t)(bx - 16) * 128 * 2048
                                : Wv + (size_t)(bx - 20) * 128 * 2048;
  const int lrow = lane >> 2;
  const int lcol = (lane & 3) * 8;

  f32x4 acc[4][4];
#pragma unroll
  for (int i = 0; i < 4; ++i)
#pragma unroll
    for (int j = 0; j < 4; ++j) acc[i][j] = (f32x4){0.f, 0.f, 0.f, 0.f};

  auto stage = [&](int buf, int k0) {
#pragma unroll
    for (int it = 0; it < 2; ++it) {
      const int c   = it * 4 + wave;
      const int row = c * 16 + lrow;
      async_copy16(A + (size_t)(m0 + row) * 2048 + k0 + lcol, &As[buf][c * 512]);
      async_copy16(W + (size_t)row * 2048 + k0 + lcol, &Bs[buf][c * 512]);
    }
  };

  stage(0, 0);
  __syncthreads();
  for (int k0 = 0; k0 < 2048; k0 += 32) {
    const int cur = (k0 >> 5) & 1;
    if (k0 + 32 < 2048) stage(cur ^ 1, k0 + 32);
    bf16x8 af[4], bfr[4];
#pragma unroll
    for (int mt = 0; mt < 4; ++mt)
      af[mt] = *(const bf16x8*)&As[cur][(wm * 64 + mt * 16 + l16) * 32 + quad * 8];
#pragma unroll
    for (int nt = 0; nt < 4; ++nt)
      bfr[nt] = *(const bf16x8*)&Bs[cur][(wn * 64 + nt * 16 + l16) * 32 + quad * 8];
#pragma unroll
    for (int mt = 0; mt < 4; ++mt)
#pragma unroll
      for (int nt = 0; nt < 4; ++nt)
        acc[mt][nt] = __builtin_amdgcn_mfma_f32_16x16x32_bf16(
            af[mt], bfr[nt], acc[mt][nt], 0, 0, 0);
    __syncthreads();
  }

  // fused RoPE (Q and K regions, wn==0 waves only; wave-uniform branch)
  if (region < 2 && wn == 0) {
#pragma unroll
    for (int nt = 0; nt < 2; ++nt) {
      const int d = nt * 16 + l16;  // 0..31
      const float invf = exp2f(-(float)d * 0.41524101186091903f);  // 10000^(-d/32)
#pragma unroll
      for (int mt = 0; mt < 4; ++mt)
#pragma unroll
        for (int r = 0; r < 4; ++r) {
          const int pos = (m0 + wm * 64 + mt * 16 + quad * 4 + r) & (S_LEN - 1);
          float s, c;
          __sincosf((float)pos * invf, &s, &c);
          const float x1 = acc[mt][nt][r], x2 = acc[mt][nt + 2][r];
          acc[mt][nt][r]     = x1 * c - x2 * s;
          acc[mt][nt + 2][r] = x2 * c + x1 * s;
        }
    }
  }

  if (region == 0) {  // Q: [tok][2048]
#pragma unroll
    for (int mt = 0; mt < 4; ++mt)
#pragma unroll
      for (int nt = 0; nt < 4; ++nt)
#pragma unroll
        for (int r = 0; r < 4; ++r) {
          const int row = m0 + wm * 64 + mt * 16 + quad * 4 + r;
          const int col = bx * 128 + wn * 64 + nt * 16 + l16;
          Qo[(size_t)row * 2048 + col] = (bf16)acc[mt][nt][r];
        }
  } else if (region == 1) {  // K: [tok][512]
#pragma unroll
    for (int mt = 0; mt < 4; ++mt)
#pragma unroll
      for (int nt = 0; nt < 4; ++nt)
#pragma unroll
        for (int r = 0; r < 4; ++r) {
          const int row = m0 + wm * 64 + mt * 16 + quad * 4 + r;
          const int col = (bx - 16) * 128 + wn * 64 + nt * 16 + l16;
          Ko[(size_t)row * 512 + col] = (bf16)acc[mt][nt][r];
        }
  } else {  // V: transposed -> vt[(b*4+kv)*128 + d][s]; 4 consecutive s/lane
#pragma unroll
    for (int mt = 0; mt < 4; ++mt) {
      const int row0 = m0 + wm * 64 + mt * 16 + quad * 4;
      const int b = row0 >> 11, s0 = row0 & (S_LEN - 1);
#pragma unroll
      for (int nt = 0; nt < 4; ++nt) {
        const int colv = (bx - 20) * 128 + wn * 64 + nt * 16 + l16;  // 0..511
        const int kvh = colv >> 7, d = colv & 127;
        bf16x4 t = {(bf16)acc[mt][nt][0], (bf16)acc[mt][nt][1],
                    (bf16)acc[mt][nt][2], (bf16)acc[mt][nt][3]};
        *(bf16x4*)(Vt + ((size_t)(b * NH_KV + kvh) * HD_ + d) * S_LEN + s0) = t;
      }
    }
  }
}

// ---------------- flash attention, S^T formulation --------------------------
#define KS_STRIDE 136   // 64 keys x 128 d, +8 pad
#define VT_STRIDE 72    // 128 d x 64 keys, +8 pad

__global__ __launch_bounds__(256)
void attn_kernel(const bf16* __restrict__ Qg, const bf16* __restrict__ Kg,
                 const bf16* __restrict__ Vtg, bf16* __restrict__ Og) {
  __shared__ __align__(16) bf16 Ks[64 * KS_STRIDE];   // K tile [key][d]
  __shared__ __align__(16) bf16 Vt[128 * VT_STRIDE];  // V^T tile [d][key]
#if !HAVE_MFMA16
  __shared__ __align__(16) bf16 Pb[4][16 * 72];
#endif
  const int tid  = threadIdx.x;
  const int wave = tid >> 6, lane = tid & 63;
  const int quad = lane >> 4, l16 = lane & 15;
  const int qt = blockIdx.x, h = blockIdx.y, b = blockIdx.z;
  const int kv = h >> 2;
  const int q0 = qt * 64;
  const int tok0 = b * S_LEN;
  const float scale = 0.08838834764831845f;  // 1/sqrt(128)
  const int q = q0 + wave * 16 + l16;

  bf16x8 qf[4];
  {
    const bf16* qp = Qg + (size_t)(tok0 + q) * (NH_Q * HD_) + h * HD_ + quad * 8;
#pragma unroll
    for (int kb = 0; kb < 4; ++kb) qf[kb] = *(const bf16x8*)(qp + kb * 32);
  }

  f32x4 o[8];
#pragma unroll
  for (int dt = 0; dt < 8; ++dt) o[dt] = (f32x4){0.f, 0.f, 0.f, 0.f};
  float m_run = -__builtin_inff(), l_run = 0.f;

  int kt_begin = q0 - WIN;
  if (kt_begin < 0) kt_begin = 0;
  const int kt_end = q0 + 64;
  const bf16* vt_base = Vtg + (size_t)(b * NH_KV + kv) * HD_ * S_LEN;

  for (int kt = kt_begin; kt < kt_end; kt += 64) {
    __syncthreads();
#pragma unroll
    for (int it = 0; it < 4; ++it) {
      int vid = tid + it * 256;
      int key = vid >> 4, dblk = vid & 15;
      bf16x8 v = *(const bf16x8*)(Kg + (size_t)(tok0 + kt + key) * (NH_KV * HD_)
                                  + kv * HD_ + dblk * 8);
      *(bf16x8*)&Ks[key * KS_STRIDE + dblk * 8] = v;
    }
#pragma unroll
    for (int it = 0; it < 4; ++it) {
      int vid = tid + it * 256;
      int d = vid >> 3, kblk = vid & 7;
      bf16x8 v = *(const bf16x8*)(vt_base + (size_t)d * S_LEN + kt + kblk * 8);
      *(bf16x8*)&Vt[d * VT_STRIDE + kblk * 8] = v;
    }
    __syncthreads();

    f32x4 st[4];
#pragma unroll
    for (int nt = 0; nt < 4; ++nt) {
      f32x4 acc = (f32x4){0.f, 0.f, 0.f, 0.f};
#pragma unroll
      for (int kb = 0; kb < 4; ++kb) {
        bf16x8 kf = *(const bf16x8*)&Ks[(nt * 16 + l16) * KS_STRIDE + kb * 32 + quad * 8];
        acc = __builtin_amdgcn_mfma_f32_16x16x32_bf16(kf, qf[kb], acc, 0, 0, 0);
      }
      st[nt] = acc;
    }
#pragma unroll
    for (int nt = 0; nt < 4; ++nt)
#pragma unroll
      for (int r = 0; r < 4; ++r) {
        int key = kt + nt * 16 + quad * 4 + r;
        bool ok = (key <= q) && (key > q - WIN);
        st[nt][r] = ok ? st[nt][r] * scale : -__builtin_inff();
      }
    float mx = -__builtin_inff();
#pragma unroll
    for (int nt = 0; nt < 4; ++nt)
#pragma unroll
      for (int r = 0; r < 4; ++r) mx = fmaxf(mx, st[nt][r]);
    mx = fmaxf(mx, __shfl_xor(mx, 16, 64));
    mx = fmaxf(mx, __shfl_xor(mx, 32, 64));
    float mnew = fmaxf(m_run, mx);
    float msub = (mnew == -__builtin_inff()) ? 0.f : mnew;
    float alpha = __expf(m_run - msub);
    m_run = mnew;
    float p[4][4], psum = 0.f;
#pragma unroll
    for (int nt = 0; nt < 4; ++nt)
#pragma unroll
      for (int r = 0; r < 4; ++r) {
        p[nt][r] = __expf(st[nt][r] - msub);
        psum += p[nt][r];
      }
    psum += __shfl_xor(psum, 16, 64);
    psum += __shfl_xor(psum, 32, 64);
    l_run = l_run * alpha + psum;
#pragma unroll
    for (int dt = 0; dt < 8; ++dt) o[dt] *= alpha;

#if HAVE_MFMA16
    s16x4 pb[4];
#pragma unroll
    for (int nt = 0; nt < 4; ++nt)
#pragma unroll
      for (int r = 0; r < 4; ++r) {
        union { __bf16 h; short s; } u;
        u.h = (bf16)p[nt][r];
        pb[nt][r] = u.s;
      }
#pragma unroll
    for (int dt = 0; dt < 8; ++dt)
#pragma unroll
      for (int nt = 0; nt < 4; ++nt) {
        s16x4 vf = *(const s16x4*)&Vt[(dt * 16 + l16) * VT_STRIDE + nt * 16 + quad * 4];
        o[dt] = __builtin_amdgcn_mfma_f32_16x16x16bf16_1k(vf, pb[nt], o[dt], 0, 0, 0);
      }
#else
#pragma unroll
    for (int nt = 0; nt < 4; ++nt) {
      bf16x4 t;
#pragma unroll
      for (int r = 0; r < 4; ++r) t[r] = (bf16)p[nt][r];
      *(bf16x4*)&Pb[wave][l16 * 72 + nt * 16 + quad * 4] = t;
    }
    __syncthreads();
    bf16x8 pf[2];
    pf[0] = *(const bf16x8*)&Pb[wave][l16 * 72 + quad * 8];
    pf[1] = *(const bf16x8*)&Pb[wave][l16 * 72 + 32 + quad * 8];
#pragma unroll
    for (int dt = 0; dt < 8; ++dt)
#pragma unroll
      for (int kb = 0; kb < 2; ++kb) {
        bf16x8 vf = *(const bf16x8*)&Vt[(dt * 16 + l16) * VT_STRIDE + kb * 32 + quad * 8];
        o[dt] = __builtin_amdgcn_mfma_f32_16x16x32_bf16(vf, pf[kb], o[dt], 0, 0, 0);
      }
#endif
  }

  float inv = 1.f / l_run;
  __syncthreads();
#pragma unroll
  for (int dt = 0; dt < 8; ++dt) {
    bf16x4 t;
#pragma unroll
    for (int r = 0; r < 4; ++r) t[r] = (bf16)(o[dt][r] * inv);
    *(bf16x4*)&Ks[(wave * 16 + l16) * KS_STRIDE + dt * 16 + quad * 4] = t;
  }
  __syncthreads();
#pragma unroll
  for (int it = 0; it < 4; ++it) {
    int idx = tid + it * 256;
    int row = idx >> 4, chunk = idx & 15;
    bf16x8 v = *(const bf16x8*)&Ks[row * KS_STRIDE + chunk * 8];
    *(bf16x8*)(Og + (size_t)(tok0 + q0 + row) * (NH_Q * HD_) + h * HD_ + chunk * 8) = v;
  }
}

// ---------------- launcher ----------------
extern "C" void kernel_launch(void* const* d_in, const int* in_sizes, int n_in,
                              void* d_out, int out_size, void* d_ws, size_t ws_size,
                              hipStream_t stream) {
  const float* hs = (const float*)d_in[0];
  const float* Wq = (const float*)d_in[1];
  const float* Wk = (const float*)d_in[2];
  const float* Wv = (const float*)d_in[3];
  const float* Wo = (const float*)d_in[4];
  float* out = (float*)d_out;

  char* w = (char*)d_ws;
  bf16* hsb = (bf16*)w; w += (size_t)NTOK * 2048 * 2;   // 16.8 MB
  bf16* wqb = (bf16*)w; w += (size_t)2048 * 2048 * 2;   //  8.4 MB
  bf16* wkb = (bf16*)w; w += (size_t)512 * 2048 * 2;    //  2.1 MB
  bf16* wvb = (bf16*)w; w += (size_t)512 * 2048 * 2;    //  2.1 MB
  bf16* wob = (bf16*)w; w += (size_t)2048 * 2048 * 2;   //  8.4 MB
  bf16* qb  = (bf16*)w; w += (size_t)NTOK * 2048 * 2;   // 16.8 MB
  bf16* kb  = (bf16*)w; w += (size_t)NTOK * 512 * 2;    //  4.2 MB
  bf16* vtb = (bf16*)w; w += (size_t)NTOK * 512 * 2;    //  4.2 MB
  bf16* ab  = hsb;  // alias: hs_bf16 dead after QKV GEMM

  cvt_all<<<18874368 / 1024, 256, 0, stream>>>(hs, Wq, Wk, Wv, Wo,
                                               hsb, wqb, wkb, wvb, wob);

  gemm_qkv<<<dim3(24, NTOK / 128), 256, 0, stream>>>(hsb, wqb, wkb, wvb,
                                                     qb, kb, vtb);

  attn_kernel<<<dim3(S_LEN / 64, NH_Q, 2), 256, 0, stream>>>(qb, kb, vtb, ab);

  gemm_bt<float><<<dim3(2048 / 128, NTOK / 128), 256, 0, stream>>>(
      ab, wob, out, NTOK, 2048, 2048);
}

// Round 5
// 301.687 us; speedup vs baseline: 1.4559x; 1.0060x over previous
//
#include <hip/hip_runtime.h>
#include <cstdint>
#include <cstddef>

typedef __bf16 bf16;
typedef __attribute__((ext_vector_type(8))) __bf16 bf16x8;
typedef __attribute__((ext_vector_type(4))) __bf16 bf16x4;
typedef __attribute__((ext_vector_type(4))) float f32x4;
typedef __attribute__((ext_vector_type(4))) short s16x4;

#define S_LEN   2048
#define WIN     512
#define NH_Q    16
#define NH_KV   4
#define HD_     128
#define NTOK    4096   // B * S

#if defined(__has_builtin)
#if __has_builtin(__builtin_amdgcn_mfma_f32_16x16x16bf16_1k)
#define HAVE_MFMA16 1
#endif
#endif
#ifndef HAVE_MFMA16
#define HAVE_MFMA16 0
#endif

// async global->LDS, 16B per lane; LDS dest = wave-uniform base + lane*16
__device__ __forceinline__ void async_copy16(const void* g, void* l) {
  __builtin_amdgcn_global_load_lds(
      (const __attribute__((address_space(1))) void*)g,
      (__attribute__((address_space(3))) void*)l, 16, 0, 0);
}

// ---------------- fp32 -> bf16 convert, all 5 arrays in one launch ----------
__global__ __launch_bounds__(256)
void cvt_all(const float* __restrict__ hs, const float* __restrict__ wq,
             const float* __restrict__ wk, const float* __restrict__ wv,
             const float* __restrict__ wo, bf16* __restrict__ hsb,
             bf16* __restrict__ wqb, bf16* __restrict__ wkb,
             bf16* __restrict__ wvb, bf16* __restrict__ wob) {
  long i = ((long)blockIdx.x * 256 + threadIdx.x) * 4;  // < 18874368
  const float* in;
  bf16* out;
  if (i < 8388608)       { in = hs + i;            out = hsb + i; }
  else if (i < 12582912) { in = wq + (i - 8388608); out = wqb + (i - 8388608); }
  else if (i < 13631488) { in = wk + (i - 12582912); out = wkb + (i - 12582912); }
  else if (i < 14680064) { in = wv + (i - 13631488); out = wvb + (i - 13631488); }
  else                   { in = wo + (i - 14680064); out = wob + (i - 14680064); }
  float4 v = *(const float4*)in;
  bf16x4 t = {(bf16)v.x, (bf16)v.y, (bf16)v.z, (bf16)v.w};
  *(bf16x4*)out = t;
}

// ---------------- GEMM: C[M][N] = A[M][K] @ W[N][K]^T -----------------------
// 64x128 tile (was 128x128): halves per-block work to DOUBLE the grid --
// 1024-1536 blocks = 4-6 blocks/CU resident (grid was the occupancy cap at
// 2-3/CU; dbuf alone was neutral because the compiler drains vmcnt(0) at
// every barrier -- more resident waves is what hides that drain, m114).
// 4 waves as 2x2; each wave 32x64 = 2x4 MFMAs of 16x16x32. LDS 24 KB dbuf.
template <typename OutT>
__global__ __launch_bounds__(256)
void gemm_bt(const bf16* __restrict__ A, const bf16* __restrict__ W,
             OutT* __restrict__ C, int M, int N, int K) {
  __shared__ __align__(16) bf16 As[2][64 * 32];
  __shared__ __align__(16) bf16 Bs[2][128 * 32];
  const int tid  = threadIdx.x;
  const int wave = tid >> 6, lane = tid & 63;
  const int quad = lane >> 4, l16 = lane & 15;
  const int wm = wave >> 1, wn = wave & 1;
  const int m0 = blockIdx.y * 64, n0 = blockIdx.x * 128;
  const int lrow = lane >> 2;
  const int lcol = (lane & 3) * 8;

  f32x4 acc[2][4];
#pragma unroll
  for (int i = 0; i < 2; ++i)
#pragma unroll
    for (int j = 0; j < 4; ++j) acc[i][j] = (f32x4){0.f, 0.f, 0.f, 0.f};

  auto stage = [&](int buf, int k0) {
    // A: 64 rows = 4 chunks of 16, one per wave
    async_copy16(A + (size_t)(m0 + wave * 16 + lrow) * K + k0 + lcol,
                 &As[buf][wave * 512]);
    // B: 128 rows = 8 chunks of 16
#pragma unroll
    for (int it = 0; it < 2; ++it) {
      const int c = it * 4 + wave;
      async_copy16(W + (size_t)(n0 + c * 16 + lrow) * K + k0 + lcol,
                   &Bs[buf][c * 512]);
    }
  };

  stage(0, 0);
  __syncthreads();
  for (int k0 = 0; k0 < K; k0 += 32) {
    const int cur = (k0 >> 5) & 1;
    if (k0 + 32 < K) stage(cur ^ 1, k0 + 32);
    bf16x8 af[2], bfr[4];
#pragma unroll
    for (int mt = 0; mt < 2; ++mt)
      af[mt] = *(const bf16x8*)&As[cur][(wm * 32 + mt * 16 + l16) * 32 + quad * 8];
#pragma unroll
    for (int nt = 0; nt < 4; ++nt)
      bfr[nt] = *(const bf16x8*)&Bs[cur][(wn * 64 + nt * 16 + l16) * 32 + quad * 8];
#pragma unroll
    for (int mt = 0; mt < 2; ++mt)
#pragma unroll
      for (int nt = 0; nt < 4; ++nt)
        acc[mt][nt] = __builtin_amdgcn_mfma_f32_16x16x32_bf16(
            af[mt], bfr[nt], acc[mt][nt], 0, 0, 0);
    __syncthreads();
  }
#pragma unroll
  for (int mt = 0; mt < 2; ++mt)
#pragma unroll
    for (int nt = 0; nt < 4; ++nt)
#pragma unroll
      for (int r = 0; r < 4; ++r) {
        const int row = m0 + wm * 32 + mt * 16 + quad * 4 + r;
        const int col = n0 + wn * 64 + nt * 16 + l16;
        C[(size_t)row * N + col] = (OutT)acc[mt][nt][r];
      }
}

// ---------------- fused QKV GEMM + RoPE + V-transpose (64x128 tiles) --------
// grid.x = 24: bx 0..15 -> Q, 16..19 -> K, 20..23 -> V. grid.y = 64.
__global__ __launch_bounds__(256)
void gemm_qkv(const bf16* __restrict__ A, const bf16* __restrict__ Wq,
              const bf16* __restrict__ Wk, const bf16* __restrict__ Wv,
              bf16* __restrict__ Qo, bf16* __restrict__ Ko,
              bf16* __restrict__ Vt) {
  __shared__ __align__(16) bf16 As[2][64 * 32];
  __shared__ __align__(16) bf16 Bs[2][128 * 32];
  const int tid  = threadIdx.x;
  const int wave = tid >> 6, lane = tid & 63;
  const int quad = lane >> 4, l16 = lane & 15;
  const int wm = wave >> 1, wn = wave & 1;
  const int bx = blockIdx.x;
  const int m0 = blockIdx.y * 64;
  const int region = (bx < 16) ? 0 : (bx < 20 ? 1 : 2);
  const bf16* W = (region == 0) ? Wq + (size_t)bx * 128 * 2048
                : (region == 1) ? Wk + (size_t)(bx - 16) * 128 * 2048
                                : Wv + (size_t)(bx - 20) * 128 * 2048;
  const int lrow = lane >> 2;
  const int lcol = (lane & 3) * 8;

  f32x4 acc[2][4];
#pragma unroll
  for (int i = 0; i < 2; ++i)
#pragma unroll
    for (int j = 0; j < 4; ++j) acc[i][j] = (f32x4){0.f, 0.f, 0.f, 0.f};

  auto stage = [&](int buf, int k0) {
    async_copy16(A + (size_t)(m0 + wave * 16 + lrow) * 2048 + k0 + lcol,
                 &As[buf][wave * 512]);
#pragma unroll
    for (int it = 0; it < 2; ++it) {
      const int c = it * 4 + wave;
      async_copy16(W + (size_t)(c * 16 + lrow) * 2048 + k0 + lcol,
                   &Bs[buf][c * 512]);
    }
  };

  stage(0, 0);
  __syncthreads();
  for (int k0 = 0; k0 < 2048; k0 += 32) {
    const int cur = (k0 >> 5) & 1;
    if (k0 + 32 < 2048) stage(cur ^ 1, k0 + 32);
    bf16x8 af[2], bfr[4];
#pragma unroll
    for (int mt = 0; mt < 2; ++mt)
      af[mt] = *(const bf16x8*)&As[cur][(wm * 32 + mt * 16 + l16) * 32 + quad * 8];
#pragma unroll
    for (int nt = 0; nt < 4; ++nt)
      bfr[nt] = *(const bf16x8*)&Bs[cur][(wn * 64 + nt * 16 + l16) * 32 + quad * 8];
#pragma unroll
    for (int mt = 0; mt < 2; ++mt)
#pragma unroll
      for (int nt = 0; nt < 4; ++nt)
        acc[mt][nt] = __builtin_amdgcn_mfma_f32_16x16x32_bf16(
            af[mt], bfr[nt], acc[mt][nt], 0, 0, 0);
    __syncthreads();
  }

  // fused RoPE (Q and K regions, wn==0 waves only; wave-uniform branch)
  if (region < 2 && wn == 0) {
#pragma unroll
    for (int nt = 0; nt < 2; ++nt) {
      const int d = nt * 16 + l16;  // 0..31
      const float invf = exp2f(-(float)d * 0.41524101186091903f);  // 10000^(-d/32)
#pragma unroll
      for (int mt = 0; mt < 2; ++mt)
#pragma unroll
        for (int r = 0; r < 4; ++r) {
          const int pos = (m0 + wm * 32 + mt * 16 + quad * 4 + r) & (S_LEN - 1);
          float s, c;
          __sincosf((float)pos * invf, &s, &c);
          const float x1 = acc[mt][nt][r], x2 = acc[mt][nt + 2][r];
          acc[mt][nt][r]     = x1 * c - x2 * s;
          acc[mt][nt + 2][r] = x2 * c + x1 * s;
        }
    }
  }

  if (region == 0) {  // Q: [tok][2048]
#pragma unroll
    for (int mt = 0; mt < 2; ++mt)
#pragma unroll
      for (int nt = 0; nt < 4; ++nt)
#pragma unroll
        for (int r = 0; r < 4; ++r) {
          const int row = m0 + wm * 32 + mt * 16 + quad * 4 + r;
          const int col = bx * 128 + wn * 64 + nt * 16 + l16;
          Qo[(size_t)row * 2048 + col] = (bf16)acc[mt][nt][r];
        }
  } else if (region == 1) {  // K: [tok][512]
#pragma unroll
    for (int mt = 0; mt < 2; ++mt)
#pragma unroll
      for (int nt = 0; nt < 4; ++nt)
#pragma unroll
        for (int r = 0; r < 4; ++r) {
          const int row = m0 + wm * 32 + mt * 16 + quad * 4 + r;
          const int col = (bx - 16) * 128 + wn * 64 + nt * 16 + l16;
          Ko[(size_t)row * 512 + col] = (bf16)acc[mt][nt][r];
        }
  } else {  // V: transposed -> vt[(b*4+kv)*128 + d][s]; 4 consecutive s/lane
#pragma unroll
    for (int mt = 0; mt < 2; ++mt) {
      const int row0 = m0 + wm * 32 + mt * 16 + quad * 4;
      const int b = row0 >> 11, s0 = row0 & (S_LEN - 1);
#pragma unroll
      for (int nt = 0; nt < 4; ++nt) {
        const int colv = (bx - 20) * 128 + wn * 64 + nt * 16 + l16;  // 0..511
        const int kvh = colv >> 7, d = colv & 127;
        bf16x4 t = {(bf16)acc[mt][nt][0], (bf16)acc[mt][nt][1],
                    (bf16)acc[mt][nt][2], (bf16)acc[mt][nt][3]};
        *(bf16x4*)(Vt + ((size_t)(b * NH_KV + kvh) * HD_ + d) * S_LEN + s0) = t;
      }
    }
  }
}

// ---------------- flash attention, S^T formulation --------------------------
#define KS_STRIDE 136   // 64 keys x 128 d, +8 pad
#define VT_STRIDE 72    // 128 d x 64 keys, +8 pad

__global__ __launch_bounds__(256)
void attn_kernel(const bf16* __restrict__ Qg, const bf16* __restrict__ Kg,
                 const bf16* __restrict__ Vtg, bf16* __restrict__ Og) {
  __shared__ __align__(16) bf16 Ks[64 * KS_STRIDE];   // K tile [key][d]
  __shared__ __align__(16) bf16 Vt[128 * VT_STRIDE];  // V^T tile [d][key]
#if !HAVE_MFMA16
  __shared__ __align__(16) bf16 Pb[4][16 * 72];
#endif
  const int tid  = threadIdx.x;
  const int wave = tid >> 6, lane = tid & 63;
  const int quad = lane >> 4, l16 = lane & 15;
  const int qt = blockIdx.x, h = blockIdx.y, b = blockIdx.z;
  const int kv = h >> 2;
  const int q0 = qt * 64;
  const int tok0 = b * S_LEN;
  const float scale = 0.08838834764831845f;  // 1/sqrt(128)
  const int q = q0 + wave * 16 + l16;

  bf16x8 qf[4];
  {
    const bf16* qp = Qg + (size_t)(tok0 + q) * (NH_Q * HD_) + h * HD_ + quad * 8;
#pragma unroll
    for (int kb = 0; kb < 4; ++kb) qf[kb] = *(const bf16x8*)(qp + kb * 32);
  }

  f32x4 o[8];
#pragma unroll
  for (int dt = 0; dt < 8; ++dt) o[dt] = (f32x4){0.f, 0.f, 0.f, 0.f};
  float m_run = -__builtin_inff(), l_run = 0.f;

  int kt_begin = q0 - WIN;
  if (kt_begin < 0) kt_begin = 0;
  const int kt_end = q0 + 64;
  const bf16* vt_base = Vtg + (size_t)(b * NH_KV + kv) * HD_ * S_LEN;

  for (int kt = kt_begin; kt < kt_end; kt += 64) {
    __syncthreads();
#pragma unroll
    for (int it = 0; it < 4; ++it) {
      int vid = tid + it * 256;
      int key = vid >> 4, dblk = vid & 15;
      bf16x8 v = *(const bf16x8*)(Kg + (size_t)(tok0 + kt + key) * (NH_KV * HD_)
                                  + kv * HD_ + dblk * 8);
      *(bf16x8*)&Ks[key * KS_STRIDE + dblk * 8] = v;
    }
#pragma unroll
    for (int it = 0; it < 4; ++it) {
      int vid = tid + it * 256;
      int d = vid >> 3, kblk = vid & 7;
      bf16x8 v = *(const bf16x8*)(vt_base + (size_t)d * S_LEN + kt + kblk * 8);
      *(bf16x8*)&Vt[d * VT_STRIDE + kblk * 8] = v;
    }
    __syncthreads();

    f32x4 st[4];
#pragma unroll
    for (int nt = 0; nt < 4; ++nt) {
      f32x4 acc = (f32x4){0.f, 0.f, 0.f, 0.f};
#pragma unroll
      for (int kb = 0; kb < 4; ++kb) {
        bf16x8 kf = *(const bf16x8*)&Ks[(nt * 16 + l16) * KS_STRIDE + kb * 32 + quad * 8];
        acc = __builtin_amdgcn_mfma_f32_16x16x32_bf16(kf, qf[kb], acc, 0, 0, 0);
      }
      st[nt] = acc;
    }
#pragma unroll
    for (int nt = 0; nt < 4; ++nt)
#pragma unroll
      for (int r = 0; r < 4; ++r) {
        int key = kt + nt * 16 + quad * 4 + r;
        bool ok = (key <= q) && (key > q - WIN);
        st[nt][r] = ok ? st[nt][r] * scale : -__builtin_inff();
      }
    float mx = -__builtin_inff();
#pragma unroll
    for (int nt = 0; nt < 4; ++nt)
#pragma unroll
      for (int r = 0; r < 4; ++r) mx = fmaxf(mx, st[nt][r]);
    mx = fmaxf(mx, __shfl_xor(mx, 16, 64));
    mx = fmaxf(mx, __shfl_xor(mx, 32, 64));
    float mnew = fmaxf(m_run, mx);
    float msub = (mnew == -__builtin_inff()) ? 0.f : mnew;
    float alpha = __expf(m_run - msub);
    m_run = mnew;
    float p[4][4], psum = 0.f;
#pragma unroll
    for (int nt = 0; nt < 4; ++nt)
#pragma unroll
      for (int r = 0; r < 4; ++r) {
        p[nt][r] = __expf(st[nt][r] - msub);
        psum += p[nt][r];
      }
    psum += __shfl_xor(psum, 16, 64);
    psum += __shfl_xor(psum, 32, 64);
    l_run = l_run * alpha + psum;
#pragma unroll
    for (int dt = 0; dt < 8; ++dt) o[dt] *= alpha;

#if HAVE_MFMA16
    s16x4 pb[4];
#pragma unroll
    for (int nt = 0; nt < 4; ++nt)
#pragma unroll
      for (int r = 0; r < 4; ++r) {
        union { __bf16 h; short s; } u;
        u.h = (bf16)p[nt][r];
        pb[nt][r] = u.s;
      }
#pragma unroll
    for (int dt = 0; dt < 8; ++dt)
#pragma unroll
      for (int nt = 0; nt < 4; ++nt) {
        s16x4 vf = *(const s16x4*)&Vt[(dt * 16 + l16) * VT_STRIDE + nt * 16 + quad * 4];
        o[dt] = __builtin_amdgcn_mfma_f32_16x16x16bf16_1k(vf, pb[nt], o[dt], 0, 0, 0);
      }
#else
#pragma unroll
    for (int nt = 0; nt < 4; ++nt) {
      bf16x4 t;
#pragma unroll
      for (int r = 0; r < 4; ++r) t[r] = (bf16)p[nt][r];
      *(bf16x4*)&Pb[wave][l16 * 72 + nt * 16 + quad * 4] = t;
    }
    __syncthreads();
    bf16x8 pf[2];
    pf[0] = *(const bf16x8*)&Pb[wave][l16 * 72 + quad * 8];
    pf[1] = *(const bf16x8*)&Pb[wave][l16 * 72 + 32 + quad * 8];
#pragma unroll
    for (int dt = 0; dt < 8; ++dt)
#pragma unroll
      for (int kb = 0; kb < 2; ++kb) {
        bf16x8 vf = *(const bf16x8*)&Vt[(dt * 16 + l16) * VT_STRIDE + kb * 32 + quad * 8];
        o[dt] = __builtin_amdgcn_mfma_f32_16x16x32_bf16(vf, pf[kb], o[dt], 0, 0, 0);
      }
#endif
  }

  float inv = 1.f / l_run;
  __syncthreads();
#pragma unroll
  for (int dt = 0; dt < 8; ++dt) {
    bf16x4 t;
#pragma unroll
    for (int r = 0; r < 4; ++r) t[r] = (bf16)(o[dt][r] * inv);
    *(bf16x4*)&Ks[(wave * 16 + l16) * KS_STRIDE + dt * 16 + quad * 4] = t;
  }
  __syncthreads();
#pragma unroll
  for (int it = 0; it < 4; ++it) {
    int idx = tid + it * 256;
    int row = idx >> 4, chunk = idx & 15;
    bf16x8 v = *(const bf16x8*)&Ks[row * KS_STRIDE + chunk * 8];
    *(bf16x8*)(Og + (size_t)(tok0 + q0 + row) * (NH_Q * HD_) + h * HD_ + chunk * 8) = v;
  }
}

// ---------------- launcher ----------------
extern "C" void kernel_launch(void* const* d_in, const int* in_sizes, int n_in,
                              void* d_out, int out_size, void* d_ws, size_t ws_size,
                              hipStream_t stream) {
  const float* hs = (const float*)d_in[0];
  const float* Wq = (const float*)d_in[1];
  const float* Wk = (const float*)d_in[2];
  const float* Wv = (const float*)d_in[3];
  const float* Wo = (const float*)d_in[4];
  float* out = (float*)d_out;

  char* w = (char*)d_ws;
  bf16* hsb = (bf16*)w; w += (size_t)NTOK * 2048 * 2;   // 16.8 MB
  bf16* wqb = (bf16*)w; w += (size_t)2048 * 2048 * 2;   //  8.4 MB
  bf16* wkb = (bf16*)w; w += (size_t)512 * 2048 * 2;    //  2.1 MB
  bf16* wvb = (bf16*)w; w += (size_t)512 * 2048 * 2;    //  2.1 MB
  bf16* wob = (bf16*)w; w += (size_t)2048 * 2048 * 2;   //  8.4 MB
  bf16* qb  = (bf16*)w; w += (size_t)NTOK * 2048 * 2;   // 16.8 MB
  bf16* kb  = (bf16*)w; w += (size_t)NTOK * 512 * 2;    //  4.2 MB
  bf16* vtb = (bf16*)w; w += (size_t)NTOK * 512 * 2;    //  4.2 MB
  bf16* ab  = hsb;  // alias: hs_bf16 dead after QKV GEMM

  cvt_all<<<18874368 / 1024, 256, 0, stream>>>(hs, Wq, Wk, Wv, Wo,
                                               hsb, wqb, wkb, wvb, wob);

  gemm_qkv<<<dim3(24, NTOK / 64), 256, 0, stream>>>(hsb, wqb, wkb, wvb,
                                                    qb, kb, vtb);

  attn_kernel<<<dim3(S_LEN / 64, NH_Q, 2), 256, 0, stream>>>(qb, kb, vtb, ab);

  gemm_bt<float><<<dim3(2048 / 128, NTOK / 64), 256, 0, stream>>>(
      ab, wob, out, NTOK, 2048, 2048);
}